// Round 7
// baseline (419.343 us; speedup 1.0000x reference)
//
#include <hip/hip_runtime.h>
#include <stdint.h>

#define IC   4096
#define BLK  256
#define CPT  4      // float4 chunks per thread per row: 4*4*256 = 4096
#define RPB  2      // rows interleaved per block (ILP source)

// ---- in-wave reductions (64 lanes), result broadcast ----
__device__ __forceinline__ double wsum_d(double v) {
    #pragma unroll
    for (int off = 32; off; off >>= 1) v += __shfl_xor(v, off);
    return v;
}
__device__ __forceinline__ int wsum_i(int v) {
    #pragma unroll
    for (int off = 32; off; off >>= 1) v += __shfl_xor(v, off);
    return v;
}

// 2 rows interleaved through all phases: 2x independent f64 chains in sweeps,
// reduction shfl-chains pipeline, barriers amortized (1 per phase for 2 rows).
// Per-row math identical to R6 (absmax 0.0 twice).
__global__ __launch_bounds__(BLK) void binarize_kernel(
    const float* __restrict__ x,
    const uint8_t* __restrict__ mask,
    float* __restrict__ out)
{
    __shared__ double sm_d[RPB][12];   // [row][phase*4 + wave]
    __shared__ int    sm_i[RPB][8];

    const int tid  = threadIdx.x;
    const int lane = tid & 63;
    const int wid  = tid >> 6;
    const int row0 = blockIdx.x * RPB;

    // ---- mask dtype detection ----
    const uint32_t probe = ((const uint32_t*)mask)[lane];
    const bool mask_is_bytes = __any(probe > 1u);

    // ---- load both rows ----
    float4 xq[RPB][CPT];
    #pragma unroll
    for (int r = 0; r < RPB; ++r) {
        const float4* xp = (const float4*)(x + (size_t)(row0 + r) * IC);
        #pragma unroll
        for (int i = 0; i < CPT; ++i) xq[r][i] = xp[i * BLK + tid];
    }

    uint32_t bm[RPB];
    if (mask_is_bytes) {
        #pragma unroll
        for (int r = 0; r < RPB; ++r) {
            const uint32_t* mp = (const uint32_t*)(mask + (size_t)(row0 + r) * IC);
            uint32_t b = 0;
            #pragma unroll
            for (int i = 0; i < CPT; ++i)
                b |= (((mp[i * BLK + tid] * 0x01020408u) >> 24) & 0xFu) << (4 * i);
            bm[r] = b;
        }
    } else {
        #pragma unroll
        for (int r = 0; r < RPB; ++r) {
            const int4* mp = (const int4*)mask + (size_t)(row0 + r) * (IC / 4);
            uint32_t b = 0;
            #pragma unroll
            for (int i = 0; i < CPT; ++i) {
                int4 m4 = mp[i * BLK + tid];
                b |= ((m4.x ? 1u : 0u) | (m4.y ? 2u : 0u)
                    | (m4.z ? 4u : 0u) | (m4.w ? 8u : 0u)) << (4 * i);
            }
            bm[r] = b;
        }
    }

    // ================= phase 1: masked sum + count =================
    double s[RPB];
    double dc[RPB], inv[RPB], mean1[RPB];
    bool   has[RPB];
    {
        double a0[RPB], a1[RPB];
        #pragma unroll
        for (int r = 0; r < RPB; ++r) { a0[r] = 0.0; a1[r] = 0.0; }
        #pragma unroll
        for (int i = 0; i < CPT; ++i) {
            #pragma unroll
            for (int r = 0; r < RPB; ++r) {
                a0[r] += (double)(((bm[r] >> (4*i + 0)) & 1u) ? xq[r][i].x : 0.0f);
                a1[r] += (double)(((bm[r] >> (4*i + 1)) & 1u) ? xq[r][i].y : 0.0f);
                a0[r] += (double)(((bm[r] >> (4*i + 2)) & 1u) ? xq[r][i].z : 0.0f);
                a1[r] += (double)(((bm[r] >> (4*i + 3)) & 1u) ? xq[r][i].w : 0.0f);
            }
        }
        #pragma unroll
        for (int r = 0; r < RPB; ++r) {
            double sw = wsum_d(a0[r] + a1[r]);
            int    cw = wsum_i(__popc(bm[r]));
            if (lane == 0) { sm_d[r][wid] = sw; sm_i[r][wid] = cw; }
        }
    }
    __syncthreads();
    #pragma unroll
    for (int r = 0; r < RPB; ++r) {
        s[r] = (sm_d[r][0] + sm_d[r][1]) + (sm_d[r][2] + sm_d[r][3]);
        const int c = (sm_i[r][0] + sm_i[r][1]) + (sm_i[r][2] + sm_i[r][3]);
        has[r]   = (c > 0);
        dc[r]    = (double)(has[r] ? c : 1);
        inv[r]   = 1.0 / dc[r];
        mean1[r] = has[r] ? s[r] * inv[r] : 0.0;
    }

    // ===== phase 2: sa = sum|x-mean1|, pn = sum sign(x-mean1) (masked) =====
    double scale1[RPB], mean2[RPB];
    double Ap[RPB], Am[RPB];
    {
        double p0[RPB], p1[RPB];
        int q[RPB];
        #pragma unroll
        for (int r = 0; r < RPB; ++r) { p0[r] = 0.0; p1[r] = 0.0; q[r] = 0; }
        #pragma unroll
        for (int i = 0; i < CPT; ++i) {
            #pragma unroll
            for (int r = 0; r < RPB; ++r) {
                const float e[4] = {xq[r][i].x, xq[r][i].y, xq[r][i].z, xq[r][i].w};
                #pragma unroll
                for (int k = 0; k < 4; ++k) {
                    const bool b = (bm[r] >> (4*i + k)) & 1u;
                    const double ce = (double)e[k] - mean1[r];
                    double& acc = (k & 1) ? p1[r] : p0[r];
                    acc  += b ? fabs(ce) : 0.0;
                    q[r] += b ? (int)(ce > 0.0) - (int)(ce < 0.0) : 0;
                }
            }
        }
        #pragma unroll
        for (int r = 0; r < RPB; ++r) {
            double sw = wsum_d(p0[r] + p1[r]);
            int    qw = wsum_i(q[r]);
            if (lane == 0) { sm_d[r][4 + wid] = sw; sm_i[r][4 + wid] = qw; }
        }
    }
    __syncthreads();
    #pragma unroll
    for (int r = 0; r < RPB; ++r) {
        const double sa = (sm_d[r][4] + sm_d[r][5]) + (sm_d[r][6] + sm_d[r][7]);
        const int    pn = (sm_i[r][4] + sm_i[r][5]) + (sm_i[r][6] + sm_i[r][7]);
        scale1[r] = has[r] ? sa * inv[r] : 0.0;
        // analytic mean2 (HW-validated R4/R5/R6, absmax 0.0)
        const double s2 = (s[r] - dc[r] * mean1[r]) - scale1[r] * (double)pn;
        mean2[r] = has[r] ? s2 * inv[r] : 0.0;
        Ap[r] = scale1[r] + mean1[r];
        Am[r] = -scale1[r] + mean1[r];
    }

    // ========= phase 3: sd = sum |(x - b1) - mean2| (masked) =========
    double Bp[RPB], Bm[RPB];
    {
        double d0[RPB], d1[RPB];
        #pragma unroll
        for (int r = 0; r < RPB; ++r) { d0[r] = 0.0; d1[r] = 0.0; }
        #pragma unroll
        for (int i = 0; i < CPT; ++i) {
            #pragma unroll
            for (int r = 0; r < RPB; ++r) {
                const float e[4] = {xq[r][i].x, xq[r][i].y, xq[r][i].z, xq[r][i].w};
                #pragma unroll
                for (int k = 0; k < 4; ++k) {
                    const bool b = (bm[r] >> (4*i + k)) & 1u;
                    const double xd = (double)e[k];
                    const double A  = (xd > mean1[r]) ? Ap[r]
                                    : ((xd < mean1[r]) ? Am[r] : mean1[r]);
                    const double c2 = (xd - A) - mean2[r];   // ref-exact chain
                    double& acc = (k & 1) ? d1[r] : d0[r];
                    acc += b ? fabs(c2) : 0.0;
                }
            }
        }
        #pragma unroll
        for (int r = 0; r < RPB; ++r) {
            double sw = wsum_d(d0[r] + d1[r]);
            if (lane == 0) sm_d[r][8 + wid] = sw;
        }
    }
    __syncthreads();
    #pragma unroll
    for (int r = 0; r < RPB; ++r) {
        const double sd = (sm_d[r][8] + sm_d[r][9]) + (sm_d[r][10] + sm_d[r][11]);
        const double scale2 = has[r] ? sd * inv[r] : 0.0;
        Bp[r] = scale2 + mean2[r];
        Bm[r] = -scale2 + mean2[r];
    }

    // ================= epilogue: out = (b1 + b2) on mask =================
    #pragma unroll
    for (int r = 0; r < RPB; ++r) {
        float* orow = out + (size_t)(row0 + r) * IC;
        #pragma unroll
        for (int i = 0; i < CPT; ++i) {
            const float e[4] = {xq[r][i].x, xq[r][i].y, xq[r][i].z, xq[r][i].w};
            float4 o;
            float* op = &o.x;
            #pragma unroll
            for (int k = 0; k < 4; ++k) {
                const bool b = (bm[r] >> (4*i + k)) & 1u;
                const double xd = (double)e[k];
                const double A  = (xd > mean1[r]) ? Ap[r]
                                : ((xd < mean1[r]) ? Am[r] : mean1[r]);
                const double c2 = (xd - A) - mean2[r];
                const double B  = (c2 > 0.0) ? Bp[r]
                                : ((c2 < 0.0) ? Bm[r] : mean2[r]);
                op[k] = b ? (float)(A + B) : 0.0f;
            }
            ((float4*)orow)[i * BLK + tid] = o;
        }
    }
}

extern "C" void kernel_launch(void* const* d_in, const int* in_sizes, int n_in,
                              void* d_out, int out_size, void* d_ws, size_t ws_size,
                              hipStream_t stream) {
    const float*   x    = (const float*)d_in[0];
    const uint8_t* mask = (const uint8_t*)d_in[1];
    float*         out  = (float*)d_out;

    const int rows = in_sizes[0] / IC;   // 11008 (even)
    binarize_kernel<<<rows / RPB, BLK, 0, stream>>>(x, mask, out);
}